// Round 7
// baseline (451.348 us; speedup 1.0000x reference)
//
#include <hip/hip_runtime.h>
#include <math.h>

// Kuramoto Euler integration, N=4096, 50 steps, K symmetry, ONE kernel/step.
// coupling_i = cos(th_i)*(K@sin th)_i - sin(th_i)*(K@cos th)_i
// K -> bf16 upper-tri 128x128 tiles (528 tiles = 16.5 MiB/step).
// State = (sin th, cos th) advanced by ROTATION with polynomial sin/cos of
// the small step delta -> NO trig in the hot kernel (trig only in init).
// Step-k kernel: phase 1 reconstructs sc_k redundantly per block from
// sc_{k-1} + part_{k-1} (identical fp32 op order in every block ->
// bit-identical); diag blocks persist theta_k and sc_k. Phase 2: LDS-staged
// tile (pitch-67 words; both access orders 2-way i.e. free), direct +
// transpose dots, plain float2/float4 stores into disjoint part slots.
// Ping-pong part/theta/sc buffers; no atomics, no fences; cross-launch
// visibility via stream ordering.

#define NOSC 4096
#define TILE 128
#define NPAN 32
#define NACT 528          // NPAN*(NPAN+1)/2
#define NSTEPS 50
#define DTF 0.01f
#define WPITCH 67         // 32-bit words per LDS tile row (2 bf16/word)
#define PART2N (NPAN * NPAN * TILE)   // float2 elements per part buffer

__device__ __forceinline__ float bf_lo(unsigned int w) {
  return __uint_as_float(w << 16);
}
__device__ __forceinline__ float bf_hi(unsigned int w) {
  return __uint_as_float(w & 0xFFFF0000u);
}
__device__ __forceinline__ unsigned short f2bf(float x) {
  unsigned int b = __float_as_uint(x);
  b += 0x7FFFu + ((b >> 16) & 1u);
  return (unsigned short)(b >> 16);
}
__device__ __forceinline__ int tri_offs(int bi) { return bi * (65 - bi) / 2; }
__device__ __forceinline__ void tile_decode(int t, int& bi, int& bj) {
  int b = (int)((65.0f - sqrtf(4225.0f - 8.0f * (float)t)) * 0.5f);
  while (tri_offs(b + 1) <= t) ++b;
  while (tri_offs(b) > t) --b;
  bi = b;
  bj = b + (t - tri_offs(b));
}

// one-time: sc0 = (sin phases, cos phases)
__global__ __launch_bounds__(256) void k_init_sc(
    const float* __restrict__ phases, float2* __restrict__ scInit) {
  const int i = blockIdx.x * 256 + threadIdx.x;
  const float t = phases[i];
  scInit[i] = make_float2(sinf(t), cosf(t));
}

// Upper-tri 128x128 tiles of fp32 K -> contiguous bf16 tiles.
__global__ __launch_bounds__(256) void k_convert(
    const float* __restrict__ Kmat, unsigned short* __restrict__ Kt) {
  int bi, bj;
  tile_decode(blockIdx.x, bi, bj);
  const float* src = Kmat + (size_t)(bi * TILE) * NOSC + (size_t)(bj * TILE);
  unsigned short* dst = Kt + (size_t)blockIdx.x * (TILE * TILE);
  #pragma unroll
  for (int q = 0; q < 16; ++q) {
    const int idx = q * 256 + threadIdx.x;   // float4 units
    const int r = idx >> 5;
    const int c = (idx & 31) << 2;
    const float4 f = *reinterpret_cast<const float4*>(src + (size_t)r * NOSC + c);
    ushort4 o;
    o.x = f2bf(f.x); o.y = f2bf(f.y); o.z = f2bf(f.z); o.w = f2bf(f.w);
    *reinterpret_cast<ushort4*>(dst + r * TILE + c) = o;
  }
}

// part layout (float2): part2[(p*NPAN + s)*TILE + r] = {S, C} partial
template <bool FIRST>
__global__ __launch_bounds__(256, 4) void k_step(
    const unsigned short* __restrict__ Kt, const float* __restrict__ omegas,
    const float* __restrict__ thPrev, float* __restrict__ thNext,
    const float2* __restrict__ scPrev, float2* __restrict__ scNext,
    const float2* __restrict__ partPrev, float2* __restrict__ partNext) {
  __shared__ unsigned int tile_w[TILE * WPITCH];   // 34304 B
  __shared__ float2 rowf[TILE];                    // {sin,cos} row panel bi
  __shared__ float2 colf[TILE];                    // {sin,cos} col panel bj
  __shared__ float4 colbuf[64];

  int bi, bj;
  tile_decode(blockIdx.x, bi, bj);
  const bool diag = (bi == bj);
  const int tid = threadIdx.x;
  const int lane = tid & 63;
  const int wv = tid >> 6;

  // ---- phase 1: reconstruct sc_k for this block's two panels (trig-free).
  // Identical op order for a given panel in every block -> bit-identical.
  {
    const int half = tid >> 7;          // 0 -> panel bi (rows), 1 -> bj (cols)
    const int r = tid & 127;
    const int p = half ? bj : bi;
    const int i = p * TILE + r;
    float2 sc = scPrev[i];
    if (!FIRST) {
      const float2* pb = partPrev + (size_t)p * NPAN * TILE + r;
      float aS = 0.f, aC = 0.f;
      #pragma unroll 8
      for (int s = 0; s < NPAN; ++s) {
        const float2 v = pb[(size_t)s * TILE];
        aS += v.x;
        aC += v.y;
      }
      const float delta = DTF * (omegas[i] + sc.y * aS - sc.x * aC);
      const float d2 = delta * delta;
      // sin/cos of small delta (|delta| < ~0.2): poly err < 1e-6
      const float sd =
          delta * fmaf(d2, fmaf(d2, 1.f / 120.f, -1.f / 6.f), 1.f);
      const float cd = fmaf(d2, fmaf(d2, 1.f / 24.f, -0.5f), 1.f);
      const float ns = fmaf(sc.x, cd, sc.y * sd);    // s*cd + c*sd
      const float nc = fmaf(sc.y, cd, -sc.x * sd);   // c*cd - s*sd
      sc = make_float2(ns, nc);
      if (diag && half == 0) {            // exactly one writer per i
        thNext[i] = thPrev[i] + delta;
        scNext[i] = sc;
      }
    }
    if (half == 0) rowf[r] = sc;
    else colf[r] = sc;
  }

  // ---- stage tile into LDS (pitch 67 words); 32 KB contiguous stream
  const unsigned short* g = Kt + (size_t)blockIdx.x * (TILE * TILE);
  #pragma unroll
  for (int q = 0; q < 8; ++q) {
    const int idx = q * 256 + tid;        // 16B units
    const int r = idx >> 4;
    const int c8 = (idx & 15) << 3;
    const uint4 u = *reinterpret_cast<const uint4*>(g + idx * 8);
    unsigned int* dw = &tile_w[r * WPITCH + (c8 >> 1)];
    dw[0] = u.x; dw[1] = u.y; dw[2] = u.z; dw[3] = u.w;
  }
  __syncthreads();

  // ---- phase 2: tile dots
  float aS0 = 0.f, aC0 = 0.f, aS1 = 0.f, aC1 = 0.f;
  if (wv < 2) {
    if (!diag) {
      // transpose dot: lane owns cols {2*lane, 2*lane+1}; wave wv rows wv*64..
      const int r0 = wv * 64;
      #pragma unroll 8
      for (int r = r0; r < r0 + 64; ++r) {
        const unsigned int w = tile_w[r * WPITCH + lane];  // 2-way: free
        const float2 rf = rowf[r];                         // broadcast
        const float k0 = bf_lo(w), k1 = bf_hi(w);
        aS0 = fmaf(k0, rf.x, aS0); aC0 = fmaf(k0, rf.y, aC0);
        aS1 = fmaf(k1, rf.x, aS1); aC1 = fmaf(k1, rf.y, aC1);
      }
    }
  } else {
    // direct dot: lane owns row r; streams 64 word-cols
    const int r = (wv - 2) * 64 + lane;
    const unsigned int* tp = &tile_w[r * WPITCH];          // 2-way: free
    #pragma unroll 8
    for (int c2 = 0; c2 < 64; ++c2) {
      const unsigned int w = tp[c2];
      const float2 cf0 = colf[2 * c2];                     // broadcast
      const float2 cf1 = colf[2 * c2 + 1];
      aS0 = fmaf(bf_lo(w), cf0.x, aS0); aC0 = fmaf(bf_lo(w), cf0.y, aC0);
      aS0 = fmaf(bf_hi(w), cf1.x, aS0); aC0 = fmaf(bf_hi(w), cf1.y, aC0);
    }
  }

  if (wv == 0 && !diag) colbuf[lane] = make_float4(aS0, aC0, aS1, aC1);
  __syncthreads();

  if (wv == 1 && !diag) {
    // transpose partial -> part[bj][bi], cols 2*lane, 2*lane+1 (16B store)
    const float4 p4 = colbuf[lane];
    const float4 o = make_float4(p4.x + aS0, p4.y + aC0, p4.z + aS1, p4.w + aC1);
    *reinterpret_cast<float4*>(
        &partNext[(size_t)(bj * NPAN + bi) * TILE + 2 * lane]) = o;
  }
  if (wv >= 2) {
    // direct partial -> part[bi][bj], row r (8B store)
    const int r = (wv - 2) * 64 + lane;
    partNext[(size_t)(bi * NPAN + bj) * TILE + r] = make_float2(aS0, aC0);
  }
}

__global__ __launch_bounds__(256) void k_final(
    const float* __restrict__ thPrev, const float2* __restrict__ scPrev,
    const float2* __restrict__ partPrev, const float* __restrict__ omegas,
    float* __restrict__ out) {
  const int i = blockIdx.x * 256 + threadIdx.x;
  const int p = i >> 7;
  const int r = i & 127;
  const float2 sc = scPrev[i];
  const float2* pb = partPrev + (size_t)p * NPAN * TILE + r;
  float aS = 0.f, aC = 0.f;
  #pragma unroll 8
  for (int s = 0; s < NPAN; ++s) {
    const float2 v = pb[(size_t)s * TILE];
    aS += v.x;
    aC += v.y;
  }
  out[i] = thPrev[i] + DTF * (omegas[i] + sc.y * aS - sc.x * aC);
}

// ---- fallback (ws too small): fp32 full-matrix step, 2 rows/wave
__global__ __launch_bounds__(256) void k_init_fb(
    const float* __restrict__ phases, float* __restrict__ theta,
    float* __restrict__ svec, float* __restrict__ cvec) {
  int i = blockIdx.x * blockDim.x + threadIdx.x;
  if (i < NOSC) {
    float t = phases[i];
    theta[i] = t;
    svec[i] = sinf(t);
    cvec[i] = cosf(t);
  }
}

__global__ __launch_bounds__(256, 2) void k_step_full(
    const float* __restrict__ Kf, const float* __restrict__ omegas,
    float* __restrict__ theta,
    const float* __restrict__ s_in, const float* __restrict__ c_in,
    float* __restrict__ s_out, float* __restrict__ c_out) {
  const int lane = threadIdx.x & 63;
  const int wave = threadIdx.x >> 6;
  const int row0 = (blockIdx.x << 3) + (wave << 1);
  const int row1 = row0 + 1;
  const float4* s4 = reinterpret_cast<const float4*>(s_in);
  const float4* c4 = reinterpret_cast<const float4*>(c_in);
  const float4* K40 = reinterpret_cast<const float4*>(Kf + (size_t)row0 * NOSC);
  const float4* K41 = reinterpret_cast<const float4*>(Kf + (size_t)row1 * NOSC);
  float aS0 = 0.f, aC0 = 0.f, aS1 = 0.f, aC1 = 0.f;
  #pragma unroll
  for (int ch = 0; ch < 16; ++ch) {
    const int idx = (ch << 6) + lane;
    float4 k0 = K40[idx], k1 = K41[idx], sv = s4[idx], cv = c4[idx];
    aS0 = fmaf(k0.x, sv.x, aS0); aS0 = fmaf(k0.y, sv.y, aS0);
    aS0 = fmaf(k0.z, sv.z, aS0); aS0 = fmaf(k0.w, sv.w, aS0);
    aC0 = fmaf(k0.x, cv.x, aC0); aC0 = fmaf(k0.y, cv.y, aC0);
    aC0 = fmaf(k0.z, cv.z, aC0); aC0 = fmaf(k0.w, cv.w, aC0);
    aS1 = fmaf(k1.x, sv.x, aS1); aS1 = fmaf(k1.y, sv.y, aS1);
    aS1 = fmaf(k1.z, sv.z, aS1); aS1 = fmaf(k1.w, sv.w, aS1);
    aC1 = fmaf(k1.x, cv.x, aC1); aC1 = fmaf(k1.y, cv.y, aC1);
    aC1 = fmaf(k1.z, cv.z, aC1); aC1 = fmaf(k1.w, cv.w, aC1);
  }
  #pragma unroll
  for (int off = 32; off > 0; off >>= 1) {
    aS0 += __shfl_xor(aS0, off); aC0 += __shfl_xor(aC0, off);
    aS1 += __shfl_xor(aS1, off); aC1 += __shfl_xor(aC1, off);
  }
  const int myRow = (lane == 0) ? row0 : ((lane == 1) ? row1 : -1);
  if (myRow >= 0) {
    const float accS = (lane == 0) ? aS0 : aS1;
    const float accC = (lane == 0) ? aC0 : aC1;
    const float tn = theta[myRow] +
        DTF * (omegas[myRow] + c_in[myRow] * accS - s_in[myRow] * accC);
    theta[myRow] = tn;
    s_out[myRow] = sinf(tn);
    c_out[myRow] = cosf(tn);
  }
}

extern "C" void kernel_launch(void* const* d_in, const int* in_sizes, int n_in,
                              void* d_out, int out_size, void* d_ws, size_t ws_size,
                              hipStream_t stream) {
  const float* phases = (const float*)d_in[0];
  const float* Kmat   = (const float*)d_in[1];
  const float* omegas = (const float*)d_in[2];
  float* out = (float*)d_out;

  float* ws = (float*)d_ws;
  float* thetaB[2] = {ws, ws + NOSC};
  float2* scInit = (float2*)(ws + 2 * NOSC);
  float2* scB[2] = {scInit + NOSC, scInit + 2 * NOSC};
  float2* partB[2] = {(float2*)(ws + 8 * NOSC), (float2*)(ws + 8 * NOSC) + PART2N};

  const size_t headBytes = (size_t)8 * NOSC * 4 + (size_t)2 * PART2N * 8;
  const size_t ktOff = (headBytes + 255) & ~(size_t)255;
  const size_t ktBytes = (size_t)NACT * TILE * TILE * 2;   // 16.5 MiB
  const bool useTiles = (ws_size >= ktOff + ktBytes);
  unsigned short* Kt = (unsigned short*)((char*)d_ws + ktOff);

  if (useTiles) {
    k_init_sc<<<NOSC / 256, 256, 0, stream>>>(phases, scInit);
    k_convert<<<NACT, 256, 0, stream>>>(Kmat, Kt);
    for (int k = 0; k < NSTEPS; ++k) {
      const float* thP = (k <= 1) ? phases : thetaB[(k - 1) & 1];
      float* thN = thetaB[k & 1];
      const float2* scP = (k <= 1) ? scInit : scB[(k - 1) & 1];
      float2* scN = scB[k & 1];
      const float2* pP = partB[(k - 1) & 1];   // unused when k==0
      float2* pN = partB[k & 1];
      if (k == 0) {
        k_step<true><<<NACT, 256, 0, stream>>>(Kt, omegas, thP, thN, scP, scN,
                                               pP, pN);
      } else {
        k_step<false><<<NACT, 256, 0, stream>>>(Kt, omegas, thP, thN, scP, scN,
                                                pP, pN);
      }
    }
    // theta_50 = theta_49 + dt*(omega + coupling(theta_49))
    const int kl = NSTEPS - 1;
    k_final<<<NOSC / 256, 256, 0, stream>>>(thetaB[kl & 1], scB[kl & 1],
                                            partB[kl & 1], omegas, out);
  } else {
    float* theta = ws + 0 * NOSC;
    float* sb[2] = {ws + 1 * NOSC, ws + 3 * NOSC};
    float* cb[2] = {ws + 2 * NOSC, ws + 4 * NOSC};
    k_init_fb<<<NOSC / 256, 256, 0, stream>>>(phases, theta, sb[0], cb[0]);
    for (int t = 0; t < NSTEPS; ++t) {
      k_step_full<<<NOSC / 8, 256, 0, stream>>>(
          Kmat, omegas, theta, sb[t & 1], cb[t & 1], sb[(t + 1) & 1], cb[(t + 1) & 1]);
    }
    hipMemcpyAsync(out, theta, NOSC * sizeof(float), hipMemcpyDeviceToDevice,
                   stream);
  }
}

// Round 8
// 424.249 us; speedup vs baseline: 1.0639x; 1.0639x over previous
//
#include <hip/hip_runtime.h>
#include <math.h>

// Kuramoto Euler integration, N=4096, 50 steps, K symmetry, ONE kernel/step.
// coupling_i = cos(th_i)*(K@sin th)_i - sin(th_i)*(K@cos th)_i
// K -> bf16 upper-tri 128x128 tiles (528 tiles = 16.5 MiB/step).
// State = (sin,cos) advanced by rotation with polynomial sin/cos of the
// small delta (no trig in hot kernel). Phase 1: each block redundantly
// reconstructs sc_k for its two panels from part_{k-1} (identical fp32 op
// order -> bit-identical); diag blocks persist theta/sc. Phase 2:
// REGISTER-BLOCKED dots over an LDS tile (pitch 66 words, b64/b128 reads,
// bank-bijective row striding) -> ~2.7x fewer LDS instructions than r7,
// flipping the kernel from LDS-pipe-bound to memory-bound.
// No atomics, no fences; cross-launch visibility via stream ordering.

#define NOSC 4096
#define TILE 128
#define NPAN 32
#define NACT 528          // NPAN*(NPAN+1)/2
#define NSTEPS 50
#define DTF 0.01f
#define WP 66             // 32-bit words per LDS tile row (even: b64 aligned)
#define PART2N (NPAN * NPAN * TILE)   // float2 elements per part buffer

__device__ __forceinline__ float bf_lo(unsigned int w) {
  return __uint_as_float(w << 16);
}
__device__ __forceinline__ float bf_hi(unsigned int w) {
  return __uint_as_float(w & 0xFFFF0000u);
}
__device__ __forceinline__ unsigned short f2bf(float x) {
  unsigned int b = __float_as_uint(x);
  b += 0x7FFFu + ((b >> 16) & 1u);
  return (unsigned short)(b >> 16);
}
__device__ __forceinline__ int tri_offs(int bi) { return bi * (65 - bi) / 2; }
__device__ __forceinline__ void tile_decode(int t, int& bi, int& bj) {
  int b = (int)((65.0f - sqrtf(4225.0f - 8.0f * (float)t)) * 0.5f);
  while (tri_offs(b + 1) <= t) ++b;
  while (tri_offs(b) > t) --b;
  bi = b;
  bj = b + (t - tri_offs(b));
}

__global__ __launch_bounds__(256) void k_init_sc(
    const float* __restrict__ phases, float2* __restrict__ scInit) {
  const int i = blockIdx.x * 256 + threadIdx.x;
  const float t = phases[i];
  scInit[i] = make_float2(sinf(t), cosf(t));
}

// Upper-tri 128x128 tiles of fp32 K -> contiguous bf16 tiles (row-major).
__global__ __launch_bounds__(256) void k_convert(
    const float* __restrict__ Kmat, unsigned short* __restrict__ Kt) {
  int bi, bj;
  tile_decode(blockIdx.x, bi, bj);
  const float* src = Kmat + (size_t)(bi * TILE) * NOSC + (size_t)(bj * TILE);
  unsigned short* dst = Kt + (size_t)blockIdx.x * (TILE * TILE);
  #pragma unroll
  for (int q = 0; q < 16; ++q) {
    const int idx = q * 256 + threadIdx.x;   // float4 units
    const int r = idx >> 5;
    const int c = (idx & 31) << 2;
    const float4 f = *reinterpret_cast<const float4*>(src + (size_t)r * NOSC + c);
    ushort4 o;
    o.x = f2bf(f.x); o.y = f2bf(f.y); o.z = f2bf(f.z); o.w = f2bf(f.w);
    *reinterpret_cast<ushort4*>(dst + r * TILE + c) = o;
  }
}

// part layout (float2): part2[(p*NPAN + s)*TILE + r] = {S, C} partial
template <bool FIRST>
__global__ __launch_bounds__(256, 3) void k_step(
    const unsigned short* __restrict__ Kt, const float* __restrict__ omegas,
    const float* __restrict__ thPrev, float* __restrict__ thNext,
    const float2* __restrict__ scPrev, float2* __restrict__ scNext,
    const float2* __restrict__ partPrev, float2* __restrict__ partNext) {
  __shared__ unsigned int tile_w[TILE * WP];   // 33792 B
  __shared__ float2 rowf[TILE];                // {sin,cos} row panel bi
  __shared__ float2 colf[TILE];                // {sin,cos} col panel bj
  __shared__ float4 cbuf[4][32][2];            // transpose partial sets
  __shared__ float2 dbuf[4][TILE];             // direct partial sets (by Q)

  int bi, bj;
  tile_decode(blockIdx.x, bi, bj);
  const bool diag = (bi == bj);
  const int tid = threadIdx.x;
  const int lane = tid & 63;
  const int wv = tid >> 6;

  // ---- phase 1: reconstruct sc_k for this block's two panels (trig-free).
  {
    const int half = tid >> 7;          // 0 -> panel bi (rows), 1 -> bj (cols)
    const int r = tid & 127;
    const int p = half ? bj : bi;
    const int i = p * TILE + r;
    float2 sc = scPrev[i];
    if (!FIRST) {
      const float2* pb = partPrev + (size_t)p * NPAN * TILE + r;
      float aS = 0.f, aC = 0.f;
      #pragma unroll 8
      for (int s = 0; s < NPAN; ++s) {
        const float2 v = pb[(size_t)s * TILE];
        aS += v.x;
        aC += v.y;
      }
      const float delta = DTF * (omegas[i] + sc.y * aS - sc.x * aC);
      const float d2 = delta * delta;
      const float sd =
          delta * fmaf(d2, fmaf(d2, 1.f / 120.f, -1.f / 6.f), 1.f);
      const float cd = fmaf(d2, fmaf(d2, 1.f / 24.f, -0.5f), 1.f);
      const float ns = fmaf(sc.x, cd, sc.y * sd);
      const float nc = fmaf(sc.y, cd, -sc.x * sd);
      sc = make_float2(ns, nc);
      if (diag && half == 0) {            // exactly one writer per i
        thNext[i] = thPrev[i] + delta;
        scNext[i] = sc;
      }
    }
    if (half == 0) rowf[r] = sc;
    else colf[r] = sc;
  }

  // ---- stage tile into LDS (pitch 66 words)
  const unsigned short* g = Kt + (size_t)blockIdx.x * (TILE * TILE);
  #pragma unroll
  for (int q = 0; q < 8; ++q) {
    const int idx = q * 256 + tid;        // 16B units
    const int r = idx >> 4;
    const int cw = (idx & 15) << 2;       // word offset within row
    const uint4 u = *reinterpret_cast<const uint4*>(g + idx * 8);
    unsigned int* dw = &tile_w[r * WP + cw];
    dw[0] = u.x; dw[1] = u.y; dw[2] = u.z; dw[3] = u.w;
  }
  __syncthreads();

  // ---- phase 2: register-blocked dots
  if (wv >= 2) {
    // DIRECT: out[row] += K[row][c]*f(c). Lane owns rows {g,g+32,g+64,g+96}
    // (stride-32: banks 2g+const, bijective/2-way) x 16-word col-quarter Q.
    const int gq = lane & 31;
    const int Q = ((wv - 2) << 1) | (lane >> 5);
    const int wbase = Q * 16;             // word-col base
    float accS[4] = {0.f, 0.f, 0.f, 0.f};
    float accC[4] = {0.f, 0.f, 0.f, 0.f};
    #pragma unroll
    for (int i = 0; i < 8; ++i) {
      const int wc = wbase + 2 * i;       // even word-col
      const float4 cf01 =
          *reinterpret_cast<const float4*>(&colf[2 * wc]);      // cols 4i',4i'+1
      const float4 cf23 =
          *reinterpret_cast<const float4*>(&colf[2 * wc + 2]);  // cols +2,+3
      #pragma unroll
      for (int k = 0; k < 4; ++k) {
        const uint2 w =
            *reinterpret_cast<const uint2*>(&tile_w[(gq + 32 * k) * WP + wc]);
        const float k0 = bf_lo(w.x), k1 = bf_hi(w.x);
        const float k2 = bf_lo(w.y), k3 = bf_hi(w.y);
        accS[k] = fmaf(k0, cf01.x, accS[k]); accC[k] = fmaf(k0, cf01.y, accC[k]);
        accS[k] = fmaf(k1, cf01.z, accS[k]); accC[k] = fmaf(k1, cf01.w, accC[k]);
        accS[k] = fmaf(k2, cf23.x, accS[k]); accC[k] = fmaf(k2, cf23.y, accC[k]);
        accS[k] = fmaf(k3, cf23.z, accS[k]); accC[k] = fmaf(k3, cf23.w, accC[k]);
      }
    }
    #pragma unroll
    for (int k = 0; k < 4; ++k)
      dbuf[Q][gq + 32 * k] = make_float2(accS[k], accC[k]);
  } else if (!diag) {
    // TRANSPOSE: out[c] += K[r][c]*f(r). Lane owns cols {4m..4m+3} (b64),
    // rows [wv*64 + rp*32, +32), 2-row pairing with one rowf b128.
    const int m = lane & 31;
    const int rp = lane >> 5;
    const int rbase = wv * 64 + rp * 32;
    float tS[4] = {0.f, 0.f, 0.f, 0.f};
    float tC[4] = {0.f, 0.f, 0.f, 0.f};
    #pragma unroll
    for (int t = 0; t < 16; ++t) {
      const int r0 = rbase + 2 * t;
      const float4 rf = *reinterpret_cast<const float4*>(&rowf[r0]);
      const uint2 w0 =
          *reinterpret_cast<const uint2*>(&tile_w[r0 * WP + 2 * m]);
      const uint2 w1 =
          *reinterpret_cast<const uint2*>(&tile_w[(r0 + 1) * WP + 2 * m]);
      const float a0 = bf_lo(w0.x), a1 = bf_hi(w0.x);
      const float a2 = bf_lo(w0.y), a3 = bf_hi(w0.y);
      const float b0 = bf_lo(w1.x), b1 = bf_hi(w1.x);
      const float b2 = bf_lo(w1.y), b3 = bf_hi(w1.y);
      tS[0] = fmaf(a0, rf.x, tS[0]); tC[0] = fmaf(a0, rf.y, tC[0]);
      tS[1] = fmaf(a1, rf.x, tS[1]); tC[1] = fmaf(a1, rf.y, tC[1]);
      tS[2] = fmaf(a2, rf.x, tS[2]); tC[2] = fmaf(a2, rf.y, tC[2]);
      tS[3] = fmaf(a3, rf.x, tS[3]); tC[3] = fmaf(a3, rf.y, tC[3]);
      tS[0] = fmaf(b0, rf.z, tS[0]); tC[0] = fmaf(b0, rf.w, tC[0]);
      tS[1] = fmaf(b1, rf.z, tS[1]); tC[1] = fmaf(b1, rf.w, tC[1]);
      tS[2] = fmaf(b2, rf.z, tS[2]); tC[2] = fmaf(b2, rf.w, tC[2]);
      tS[3] = fmaf(b3, rf.z, tS[3]); tC[3] = fmaf(b3, rf.w, tC[3]);
    }
    const int set = wv * 2 + rp;
    cbuf[set][m][0] = make_float4(tS[0], tC[0], tS[1], tC[1]);
    cbuf[set][m][1] = make_float4(tS[2], tC[2], tS[3], tC[3]);
  }
  __syncthreads();

  // ---- summers
  if (wv >= 2) {
    // direct: row r total = sum over 4 col-quarters
    const int r = (wv - 2) * 64 + lane;
    const float2 d0 = dbuf[0][r], d1 = dbuf[1][r];
    const float2 d2 = dbuf[2][r], d3 = dbuf[3][r];
    partNext[(size_t)(bi * NPAN + bj) * TILE + r] =
        make_float2((d0.x + d1.x) + (d2.x + d3.x),
                    (d0.y + d1.y) + (d2.y + d3.y));
  } else if (wv == 0 && !diag) {
    // transpose: cols {4m+2h, 4m+2h+1} total = sum over 4 row-sets
    const int m = lane & 31;
    const int h = lane >> 5;
    const float4 c0 = cbuf[0][m][h], c1 = cbuf[1][m][h];
    const float4 c2 = cbuf[2][m][h], c3 = cbuf[3][m][h];
    const float4 o = make_float4((c0.x + c1.x) + (c2.x + c3.x),
                                 (c0.y + c1.y) + (c2.y + c3.y),
                                 (c0.z + c1.z) + (c2.z + c3.z),
                                 (c0.w + c1.w) + (c2.w + c3.w));
    *reinterpret_cast<float4*>(
        &partNext[(size_t)(bj * NPAN + bi) * TILE + 4 * m + 2 * h]) = o;
  }
}

__global__ __launch_bounds__(256) void k_final(
    const float* __restrict__ thPrev, const float2* __restrict__ scPrev,
    const float2* __restrict__ partPrev, const float* __restrict__ omegas,
    float* __restrict__ out) {
  const int i = blockIdx.x * 256 + threadIdx.x;
  const int p = i >> 7;
  const int r = i & 127;
  const float2 sc = scPrev[i];
  const float2* pb = partPrev + (size_t)p * NPAN * TILE + r;
  float aS = 0.f, aC = 0.f;
  #pragma unroll 8
  for (int s = 0; s < NPAN; ++s) {
    const float2 v = pb[(size_t)s * TILE];
    aS += v.x;
    aC += v.y;
  }
  out[i] = thPrev[i] + DTF * (omegas[i] + sc.y * aS - sc.x * aC);
}

// ---- fallback (ws too small): fp32 full-matrix step, 2 rows/wave
__global__ __launch_bounds__(256) void k_init_fb(
    const float* __restrict__ phases, float* __restrict__ theta,
    float* __restrict__ svec, float* __restrict__ cvec) {
  int i = blockIdx.x * blockDim.x + threadIdx.x;
  if (i < NOSC) {
    float t = phases[i];
    theta[i] = t;
    svec[i] = sinf(t);
    cvec[i] = cosf(t);
  }
}

__global__ __launch_bounds__(256, 2) void k_step_full(
    const float* __restrict__ Kf, const float* __restrict__ omegas,
    float* __restrict__ theta,
    const float* __restrict__ s_in, const float* __restrict__ c_in,
    float* __restrict__ s_out, float* __restrict__ c_out) {
  const int lane = threadIdx.x & 63;
  const int wave = threadIdx.x >> 6;
  const int row0 = (blockIdx.x << 3) + (wave << 1);
  const int row1 = row0 + 1;
  const float4* s4 = reinterpret_cast<const float4*>(s_in);
  const float4* c4 = reinterpret_cast<const float4*>(c_in);
  const float4* K40 = reinterpret_cast<const float4*>(Kf + (size_t)row0 * NOSC);
  const float4* K41 = reinterpret_cast<const float4*>(Kf + (size_t)row1 * NOSC);
  float aS0 = 0.f, aC0 = 0.f, aS1 = 0.f, aC1 = 0.f;
  #pragma unroll
  for (int ch = 0; ch < 16; ++ch) {
    const int idx = (ch << 6) + lane;
    float4 k0 = K40[idx], k1 = K41[idx], sv = s4[idx], cv = c4[idx];
    aS0 = fmaf(k0.x, sv.x, aS0); aS0 = fmaf(k0.y, sv.y, aS0);
    aS0 = fmaf(k0.z, sv.z, aS0); aS0 = fmaf(k0.w, sv.w, aS0);
    aC0 = fmaf(k0.x, cv.x, aC0); aC0 = fmaf(k0.y, cv.y, aC0);
    aC0 = fmaf(k0.z, cv.z, aC0); aC0 = fmaf(k0.w, cv.w, aC0);
    aS1 = fmaf(k1.x, sv.x, aS1); aS1 = fmaf(k1.y, sv.y, aS1);
    aS1 = fmaf(k1.z, sv.z, aS1); aS1 = fmaf(k1.w, sv.w, aS1);
    aC1 = fmaf(k1.x, cv.x, aC1); aC1 = fmaf(k1.y, cv.y, aC1);
    aC1 = fmaf(k1.z, cv.z, aC1); aC1 = fmaf(k1.w, cv.w, aC1);
  }
  #pragma unroll
  for (int off = 32; off > 0; off >>= 1) {
    aS0 += __shfl_xor(aS0, off); aC0 += __shfl_xor(aC0, off);
    aS1 += __shfl_xor(aS1, off); aC1 += __shfl_xor(aC1, off);
  }
  const int myRow = (lane == 0) ? row0 : ((lane == 1) ? row1 : -1);
  if (myRow >= 0) {
    const float accS = (lane == 0) ? aS0 : aS1;
    const float accC = (lane == 0) ? aC0 : aC1;
    const float tn = theta[myRow] +
        DTF * (omegas[myRow] + c_in[myRow] * accS - s_in[myRow] * accC);
    theta[myRow] = tn;
    s_out[myRow] = sinf(tn);
    c_out[myRow] = cosf(tn);
  }
}

extern "C" void kernel_launch(void* const* d_in, const int* in_sizes, int n_in,
                              void* d_out, int out_size, void* d_ws, size_t ws_size,
                              hipStream_t stream) {
  const float* phases = (const float*)d_in[0];
  const float* Kmat   = (const float*)d_in[1];
  const float* omegas = (const float*)d_in[2];
  float* out = (float*)d_out;

  float* ws = (float*)d_ws;
  float* thetaB[2] = {ws, ws + NOSC};
  float2* scInit = (float2*)(ws + 2 * NOSC);
  float2* scB[2] = {scInit + NOSC, scInit + 2 * NOSC};
  float2* partB[2] = {(float2*)(ws + 8 * NOSC), (float2*)(ws + 8 * NOSC) + PART2N};

  const size_t headBytes = (size_t)8 * NOSC * 4 + (size_t)2 * PART2N * 8;
  const size_t ktOff = (headBytes + 255) & ~(size_t)255;
  const size_t ktBytes = (size_t)NACT * TILE * TILE * 2;   // 16.5 MiB
  const bool useTiles = (ws_size >= ktOff + ktBytes);
  unsigned short* Kt = (unsigned short*)((char*)d_ws + ktOff);

  if (useTiles) {
    k_init_sc<<<NOSC / 256, 256, 0, stream>>>(phases, scInit);
    k_convert<<<NACT, 256, 0, stream>>>(Kmat, Kt);
    for (int k = 0; k < NSTEPS; ++k) {
      const float* thP = (k <= 1) ? phases : thetaB[(k - 1) & 1];
      float* thN = thetaB[k & 1];
      const float2* scP = (k <= 1) ? scInit : scB[(k - 1) & 1];
      float2* scN = scB[k & 1];
      const float2* pP = partB[(k - 1) & 1];   // unused when k==0
      float2* pN = partB[k & 1];
      if (k == 0) {
        k_step<true><<<NACT, 256, 0, stream>>>(Kt, omegas, thP, thN, scP, scN,
                                               pP, pN);
      } else {
        k_step<false><<<NACT, 256, 0, stream>>>(Kt, omegas, thP, thN, scP, scN,
                                                pP, pN);
      }
    }
    const int kl = NSTEPS - 1;
    k_final<<<NOSC / 256, 256, 0, stream>>>(thetaB[kl & 1], scB[kl & 1],
                                            partB[kl & 1], omegas, out);
  } else {
    float* theta = ws + 0 * NOSC;
    float* sb[2] = {ws + 1 * NOSC, ws + 3 * NOSC};
    float* cb[2] = {ws + 2 * NOSC, ws + 4 * NOSC};
    k_init_fb<<<NOSC / 256, 256, 0, stream>>>(phases, theta, sb[0], cb[0]);
    for (int t = 0; t < NSTEPS; ++t) {
      k_step_full<<<NOSC / 8, 256, 0, stream>>>(
          Kmat, omegas, theta, sb[t & 1], cb[t & 1], sb[(t + 1) & 1], cb[(t + 1) & 1]);
    }
    hipMemcpyAsync(out, theta, NOSC * sizeof(float), hipMemcpyDeviceToDevice,
                   stream);
  }
}

// Round 9
// 307.617 us; speedup vs baseline: 1.4672x; 1.3791x over previous
//
#include <hip/hip_runtime.h>
#include <math.h>

// Kuramoto Euler integration, N=4096, 50 steps.
// coupling_i = cos(th_i)*(K@sin th)_i - sin(th_i)*(K@cos th)_i
// K -> bf16 once (32 MiB == aggregate L2). ONE kernel per step, 512 blocks.
// XCD-PINNED row mapping: block b -> rows (b&7)*512 + (b>>3)*8 .. +8, so
// under the round-robin blockIdx%8 -> XCD dispatch each XCD re-reads the
// SAME contiguous 4 MiB slice of K every step -> L2-resident after step 0,
// steps run at L2 BW instead of HBM. Mapping only affects speed, never
// correctness. s/c staged in LDS; 2 rows/wave; uint4 (8x bf16) K loads.

#define NOSC 4096
#define NSTEPS 50
#define DTF 0.01f

__device__ __forceinline__ float bf_lo(unsigned int w) {
  return __uint_as_float(w << 16);
}
__device__ __forceinline__ float bf_hi(unsigned int w) {
  return __uint_as_float(w & 0xFFFF0000u);
}

// fp32 K -> bf16 K (RNE), with theta/sin/cos init fused into blocks 0..15
__global__ __launch_bounds__(256) void k_convert(
    const float4* __restrict__ K4, ushort4* __restrict__ Kb,
    const float* __restrict__ phases, float* __restrict__ theta,
    float* __restrict__ s0, float* __restrict__ c0) {
  if (blockIdx.x < 16) {
    const int i = blockIdx.x * 256 + threadIdx.x;
    const float t = phases[i];
    theta[i] = t;
    s0[i] = sinf(t);
    c0[i] = cosf(t);
  }
  const int n4 = NOSC * NOSC / 4;
  for (int i = blockIdx.x * 256 + threadIdx.x; i < n4;
       i += gridDim.x * 256) {
    const float4 f = K4[i];
    ushort4 o;
    unsigned int b;
    b = __float_as_uint(f.x); b += 0x7FFFu + ((b >> 16) & 1u); o.x = (unsigned short)(b >> 16);
    b = __float_as_uint(f.y); b += 0x7FFFu + ((b >> 16) & 1u); o.y = (unsigned short)(b >> 16);
    b = __float_as_uint(f.z); b += 0x7FFFu + ((b >> 16) & 1u); o.z = (unsigned short)(b >> 16);
    b = __float_as_uint(f.w); b += 0x7FFFu + ((b >> 16) & 1u); o.w = (unsigned short)(b >> 16);
    Kb[i] = o;
  }
}

// One step: 512 blocks x 256 thr; block b -> 8 rows, XCD-pinned; 2 rows/wave.
template <bool BF16K>
__global__ __launch_bounds__(256, 2) void k_step(
    const void* __restrict__ Kp, const float* __restrict__ omegas,
    float* __restrict__ theta,
    const float* __restrict__ s_in, const float* __restrict__ c_in,
    float* __restrict__ s_out, float* __restrict__ c_out) {
  __shared__ float s_lds[NOSC];
  __shared__ float c_lds[NOSC];
  const int tid = threadIdx.x;
  const int lane = tid & 63;
  const int wv = tid >> 6;
  // XCD-pinned rows: slice (b&7) -> 512-row band; (b>>3) walks within band.
  const int base = ((blockIdx.x & 7) << 9) + ((blockIdx.x >> 3) << 3);
  const int r0 = base + 2 * wv;
  const int r1 = r0 + 1;

  // stage s/c (32 KB) into LDS, coalesced
  float4* sl4 = reinterpret_cast<float4*>(s_lds);
  float4* cl4 = reinterpret_cast<float4*>(c_lds);
  const float4* sg4 = reinterpret_cast<const float4*>(s_in);
  const float4* cg4 = reinterpret_cast<const float4*>(c_in);
  #pragma unroll
  for (int i = 0; i < 4; ++i) {
    const int idx = i * 256 + tid;
    sl4[idx] = sg4[idx];
    cl4[idx] = cg4[idx];
  }
  __syncthreads();

  float aS0 = 0.f, aC0 = 0.f, aS1 = 0.f, aC1 = 0.f;
  if (BF16K) {
    const unsigned short* Kb = reinterpret_cast<const unsigned short*>(Kp);
    const uint4* Ka = reinterpret_cast<const uint4*>(Kb + (size_t)r0 * NOSC);
    const uint4* Kc = reinterpret_cast<const uint4*>(Kb + (size_t)r1 * NOSC);
    #pragma unroll
    for (int ch = 0; ch < 8; ++ch) {
      const int idx = (ch << 6) + lane;      // uint4 index: 8 bf16 = 16B/lane
      const uint4 ka = Ka[idx];
      const uint4 kb = Kc[idx];
      const float4 sv0 = sl4[2 * idx], sv1 = sl4[2 * idx + 1];
      const float4 cv0 = cl4[2 * idx], cv1 = cl4[2 * idx + 1];
      float k;
      k = bf_lo(ka.x); aS0 = fmaf(k, sv0.x, aS0); aC0 = fmaf(k, cv0.x, aC0);
      k = bf_hi(ka.x); aS0 = fmaf(k, sv0.y, aS0); aC0 = fmaf(k, cv0.y, aC0);
      k = bf_lo(ka.y); aS0 = fmaf(k, sv0.z, aS0); aC0 = fmaf(k, cv0.z, aC0);
      k = bf_hi(ka.y); aS0 = fmaf(k, sv0.w, aS0); aC0 = fmaf(k, cv0.w, aC0);
      k = bf_lo(ka.z); aS0 = fmaf(k, sv1.x, aS0); aC0 = fmaf(k, cv1.x, aC0);
      k = bf_hi(ka.z); aS0 = fmaf(k, sv1.y, aS0); aC0 = fmaf(k, cv1.y, aC0);
      k = bf_lo(ka.w); aS0 = fmaf(k, sv1.z, aS0); aC0 = fmaf(k, cv1.z, aC0);
      k = bf_hi(ka.w); aS0 = fmaf(k, sv1.w, aS0); aC0 = fmaf(k, cv1.w, aC0);
      k = bf_lo(kb.x); aS1 = fmaf(k, sv0.x, aS1); aC1 = fmaf(k, cv0.x, aC1);
      k = bf_hi(kb.x); aS1 = fmaf(k, sv0.y, aS1); aC1 = fmaf(k, cv0.y, aC1);
      k = bf_lo(kb.y); aS1 = fmaf(k, sv0.z, aS1); aC1 = fmaf(k, cv0.z, aC1);
      k = bf_hi(kb.y); aS1 = fmaf(k, sv0.w, aS1); aC1 = fmaf(k, cv0.w, aC1);
      k = bf_lo(kb.z); aS1 = fmaf(k, sv1.x, aS1); aC1 = fmaf(k, cv1.x, aC1);
      k = bf_hi(kb.z); aS1 = fmaf(k, sv1.y, aS1); aC1 = fmaf(k, cv1.y, aC1);
      k = bf_lo(kb.w); aS1 = fmaf(k, sv1.z, aS1); aC1 = fmaf(k, cv1.z, aC1);
      k = bf_hi(kb.w); aS1 = fmaf(k, sv1.w, aS1); aC1 = fmaf(k, cv1.w, aC1);
    }
  } else {
    const float* Kf = reinterpret_cast<const float*>(Kp);
    const float4* Ka = reinterpret_cast<const float4*>(Kf + (size_t)r0 * NOSC);
    const float4* Kc = reinterpret_cast<const float4*>(Kf + (size_t)r1 * NOSC);
    #pragma unroll
    for (int ch = 0; ch < 16; ++ch) {
      const int idx = (ch << 6) + lane;
      const float4 k0 = Ka[idx], k1 = Kc[idx];
      const float4 sv = sl4[idx], cv = cl4[idx];
      aS0 = fmaf(k0.x, sv.x, aS0); aS0 = fmaf(k0.y, sv.y, aS0);
      aS0 = fmaf(k0.z, sv.z, aS0); aS0 = fmaf(k0.w, sv.w, aS0);
      aC0 = fmaf(k0.x, cv.x, aC0); aC0 = fmaf(k0.y, cv.y, aC0);
      aC0 = fmaf(k0.z, cv.z, aC0); aC0 = fmaf(k0.w, cv.w, aC0);
      aS1 = fmaf(k1.x, sv.x, aS1); aS1 = fmaf(k1.y, sv.y, aS1);
      aS1 = fmaf(k1.z, sv.z, aS1); aS1 = fmaf(k1.w, sv.w, aS1);
      aC1 = fmaf(k1.x, cv.x, aC1); aC1 = fmaf(k1.y, cv.y, aC1);
      aC1 = fmaf(k1.z, cv.z, aC1); aC1 = fmaf(k1.w, cv.w, aC1);
    }
  }

  // wave-64 butterfly; lanes 0/1 own rows r0/r1
  #pragma unroll
  for (int off = 32; off > 0; off >>= 1) {
    aS0 += __shfl_xor(aS0, off); aC0 += __shfl_xor(aC0, off);
    aS1 += __shfl_xor(aS1, off); aC1 += __shfl_xor(aC1, off);
  }
  const int myRow = (lane == 0) ? r0 : ((lane == 1) ? r1 : -1);
  if (myRow >= 0) {
    const float accS = (lane == 0) ? aS0 : aS1;
    const float accC = (lane == 0) ? aC0 : aC1;
    const float si = s_lds[myRow];
    const float ci = c_lds[myRow];
    const float tn = theta[myRow] + DTF * (omegas[myRow] + ci * accS - si * accC);
    theta[myRow] = tn;
    s_out[myRow] = sinf(tn);
    c_out[myRow] = cosf(tn);
  }
}

__global__ __launch_bounds__(256) void k_init_fb(
    const float* __restrict__ phases, float* __restrict__ theta,
    float* __restrict__ svec, float* __restrict__ cvec) {
  const int i = blockIdx.x * 256 + threadIdx.x;
  const float t = phases[i];
  theta[i] = t;
  svec[i] = sinf(t);
  cvec[i] = cosf(t);
}

extern "C" void kernel_launch(void* const* d_in, const int* in_sizes, int n_in,
                              void* d_out, int out_size, void* d_ws, size_t ws_size,
                              hipStream_t stream) {
  const float* phases = (const float*)d_in[0];
  const float* Kmat   = (const float*)d_in[1];
  const float* omegas = (const float*)d_in[2];
  float* out = (float*)d_out;

  float* ws = (float*)d_ws;
  float* theta = ws + 0 * NOSC;
  float* sb[2] = {ws + 1 * NOSC, ws + 3 * NOSC};
  float* cb[2] = {ws + 2 * NOSC, ws + 4 * NOSC};

  const size_t headBytes = (size_t)5 * NOSC * sizeof(float);
  const size_t kbOff = (headBytes + 255) & ~(size_t)255;
  const size_t kbBytes = (size_t)NOSC * NOSC * 2;
  const bool useBf16 = (ws_size >= kbOff + kbBytes);
  unsigned short* Kb = (unsigned short*)((char*)d_ws + kbOff);

  if (useBf16) {
    k_convert<<<2048, 256, 0, stream>>>((const float4*)Kmat, (ushort4*)Kb,
                                        phases, theta, sb[0], cb[0]);
    for (int t = 0; t < NSTEPS; ++t) {
      k_step<true><<<512, 256, 0, stream>>>(
          (const void*)Kb, omegas, theta, sb[t & 1], cb[t & 1],
          sb[(t + 1) & 1], cb[(t + 1) & 1]);
    }
  } else {
    k_init_fb<<<NOSC / 256, 256, 0, stream>>>(phases, theta, sb[0], cb[0]);
    for (int t = 0; t < NSTEPS; ++t) {
      k_step<false><<<512, 256, 0, stream>>>(
          (const void*)Kmat, omegas, theta, sb[t & 1], cb[t & 1],
          sb[(t + 1) & 1], cb[(t + 1) & 1]);
    }
  }
  hipMemcpyAsync(out, theta, NOSC * sizeof(float), hipMemcpyDeviceToDevice,
                 stream);
}